// Round 5
// baseline (35.234 us; speedup 1.0000x reference)
//
#include <hip/hip_runtime.h>
#include <hip/hip_bf16.h>

// Problem constants
constexpr int Bn = 4096;   // batch
constexpr int Vn = 64;     // nodes
constexpr int Hn = 512;    // hidden

typedef __attribute__((ext_vector_type(8))) short bf16x8;
typedef __attribute__((ext_vector_type(4))) float f32x4;
typedef __attribute__((ext_vector_type(8))) unsigned short u16x8;

union bfcast { u16x8 u; bf16x8 b; };

__device__ __forceinline__ unsigned short f2bf(float f) {
    union { float f; unsigned int u; } x; x.f = f;
    unsigned int u = x.u;
    u += 0x7fffu + ((u >> 16) & 1u);   // round-to-nearest-even
    return (unsigned short)(u >> 16);
}

// ---------------------------------------------------------------------------
// Prep: W1w[v][k][n] = sigmoid(adjw[v][k]) * W1[v][k-(k>v)][n]  (0 if k==v)
// stored in mfma_f32_16x16x32_bf16 B-fragment layout:
//   flat = (((v*32 + nt)*2 + ks)*64 + lane)*8 + e
//   where n = nt*16 + (lane&15), k = ks*32 + (lane>>4)*8 + e
// Block swizzle matches main_k: XCD x writes exactly the panels v in
// [x*8, x*8+8) that main_k's XCD x will read -> L2-affine producer/consumer.
// ---------------------------------------------------------------------------
__global__ void prep_w1(const float* __restrict__ adjw,
                        const float* __restrict__ W1,
                        unsigned short* __restrict__ bfrag) {
    int nb   = (blockIdx.x & 7) * 128 + (blockIdx.x >> 3);   // bijective, 1024
    int tid  = nb * 256 + threadIdx.x;                       // 262144 threads
    int lane = tid & 63;
    int ks   = (tid >> 6) & 1;
    int nt   = (tid >> 7) & 31;
    int v    = tid >> 12;

    int n     = nt * 16 + (lane & 15);
    int kbase = ks * 32 + ((lane >> 4) << 3);

    u16x8 o;
#pragma unroll
    for (int e = 0; e < 8; ++e) {
        int k = kbase + e;
        float val = 0.f;
        if (k != v) {
            float aw = adjw[v * Vn + k];
            float s  = 1.f / (1.f + __expf(-aw));
            int  j   = k - (k > v);
            val = s * W1[((size_t)(v * (Vn - 1) + j)) * Hn + n];
        }
        o[e] = f2bf(val);
    }
    *reinterpret_cast<u16x8*>(bfrag + (size_t)tid * 8) = o;
}

// ---------------------------------------------------------------------------
// Main: one WAVE = one job (64 batch rows x one v). No LDS, no barriers.
// A-fragments built in-register from x (no afrag buffer). B streamed with a
// 3-deep static double... triple-buffered prefetch. XCD-bijective swizzle
// keeps each XCD on 8 B-panels (512 KiB, L2-resident). setprio(1) around the
// MFMA pairs (independent waves -> scheduler has roles to arbitrate).
// ---------------------------------------------------------------------------
__global__ __launch_bounds__(256, 4)
void main_k(const float* __restrict__ x,
            const unsigned short* __restrict__ bfrag,
            const float* __restrict__ b1, const float* __restrict__ W2,
            const float* __restrict__ b2, float* __restrict__ out) {
    int wid  = threadIdx.x >> 6;
    int lane = threadIdx.x & 63;
    // bijective XCD swizzle: 1024 blocks = 8 XCDs x 128
    int nb   = (blockIdx.x & 7) * 128 + (blockIdx.x >> 3);
    int job  = nb * 4 + wid;             // 0..4095, v-major
    int v    = job >> 6;
    int rg   = job & 63;                 // 64-row group

    const unsigned short* bpan = bfrag + (size_t)v * 32 * 2 * 512;  // v's panel
    const float* w2row = W2 + v * Hn;
    const float* b1row = b1 + v * Hn;
    int ncol = lane & 15;

    // --- issue 3-deep B prefetch FIRST (overlaps the A-build x loads) ---
    bf16x8 pb0[3], pb1[3];
    float  pw2[3], pbv[3];
#pragma unroll
    for (int p = 0; p < 3; ++p) {
        pb0[p] = *reinterpret_cast<const bf16x8*>(bpan + (size_t)p * 1024 + 0 + lane * 8);
        pb1[p] = *reinterpret_cast<const bf16x8*>(bpan + (size_t)p * 1024 + 512 + lane * 8);
        pw2[p] = w2row[p * 16 + ncol];
        pbv[p] = b1row[p * 16 + ncol];
    }

    // --- A fragments built from x directly: b = rg*64 + m*16 + (lane&15),
    //     k = ks*32 + (lane>>4)*8 + e  (32B-aligned float8 per frag) ---
    bf16x8 a[4][2];
#pragma unroll
    for (int m = 0; m < 4; ++m)
#pragma unroll
        for (int ks = 0; ks < 2; ++ks) {
            int brow  = rg * 64 + m * 16 + (lane & 15);
            int kbase = ks * 32 + ((lane >> 4) << 3);
            const float* xp = x + (size_t)brow * Vn + kbase;
            f32x4 lo = *reinterpret_cast<const f32x4*>(xp);
            f32x4 hi = *reinterpret_cast<const f32x4*>(xp + 4);
            bfcast t;
#pragma unroll
            for (int e = 0; e < 4; ++e) {
                t.u[e]     = f2bf(lo[e]);
                t.u[e + 4] = f2bf(hi[e]);
            }
            a[m][ks] = t.b;
        }

    float partial[4][4] = {};

#pragma unroll
    for (int j = 0; j < 32; ++j) {
        const int cur = j % 3;
        if (j < 29) {
            const int nxt = j % 3;   // buffer being freed this iter is j%3; but
            // we consume it below, so prefetch into (j+3)%3 == j%3 AFTER use.
        }
#pragma unroll
        for (int m = 0; m < 4; ++m) {
            f32x4 c = {pbv[cur], pbv[cur], pbv[cur], pbv[cur]};
            __builtin_amdgcn_s_setprio(1);
            c = __builtin_amdgcn_mfma_f32_16x16x32_bf16(a[m][0], pb0[cur], c, 0, 0, 0);
            c = __builtin_amdgcn_mfma_f32_16x16x32_bf16(a[m][1], pb1[cur], c, 0, 0, 0);
            __builtin_amdgcn_s_setprio(0);
#pragma unroll
            for (int r = 0; r < 4; ++r)
                partial[m][r] = fmaf(fmaxf(c[r], 0.f), pw2[cur], partial[m][r]);
        }
        // refill the slot we just consumed with tile j+3
        if (j < 29) {
            pb0[cur] = *reinterpret_cast<const bf16x8*>(
                bpan + (size_t)(j + 3) * 1024 + 0 + lane * 8);
            pb1[cur] = *reinterpret_cast<const bf16x8*>(
                bpan + (size_t)(j + 3) * 1024 + 512 + lane * 8);
            pw2[cur] = w2row[(j + 3) * 16 + ncol];
            pbv[cur] = b1row[(j + 3) * 16 + ncol];
        }
    }

    // reduce over the 16-lane column group (bits 0..3 of lane)
#pragma unroll
    for (int m = 0; m < 4; ++m)
#pragma unroll
        for (int r = 0; r < 4; ++r) {
            float s = partial[m][r];
            s += __shfl_xor(s, 1);
            s += __shfl_xor(s, 2);
            s += __shfl_xor(s, 4);
            s += __shfl_xor(s, 8);
            partial[m][r] = s;
        }

    float b2v = b2[v];
    if ((lane & 15) == 0) {
        int hi = lane >> 4;
#pragma unroll
        for (int m = 0; m < 4; ++m)
#pragma unroll
            for (int r = 0; r < 4; ++r) {
                int row = rg * 64 + m * 16 + hi * 4 + r;
                out[(size_t)row * Vn + v] = partial[m][r] + b2v;
            }
    }
}

extern "C" void kernel_launch(void* const* d_in, const int* in_sizes, int n_in,
                              void* d_out, int out_size, void* d_ws, size_t ws_size,
                              hipStream_t stream) {
    const float* x    = (const float*)d_in[0];
    const float* adjw = (const float*)d_in[1];
    const float* W1   = (const float*)d_in[2];
    const float* b1   = (const float*)d_in[3];
    const float* W2   = (const float*)d_in[4];
    const float* b2   = (const float*)d_in[5];
    float* out = (float*)d_out;

    // workspace: bfrag = 64*64*512 u16 (4 MiB)
    unsigned short* bfrag = (unsigned short*)d_ws;

    prep_w1<<<1024, 256, 0, stream>>>(adjw, W1, bfrag);
    main_k<<<1024, 256, 0, stream>>>(x, bfrag, b1, W2, b2, out);
}

// Round 6
// 33.513 us; speedup vs baseline: 1.0514x; 1.0514x over previous
//
#include <hip/hip_runtime.h>
#include <hip/hip_bf16.h>

// Problem constants
constexpr int Bn = 4096;   // batch
constexpr int Vn = 64;     // nodes
constexpr int Hn = 512;    // hidden

typedef __attribute__((ext_vector_type(8))) short bf16x8;
typedef __attribute__((ext_vector_type(4))) float f32x4;
typedef __attribute__((ext_vector_type(8))) unsigned short u16x8;

union bfcast { u16x8 u; bf16x8 b; };

__device__ __forceinline__ unsigned short f2bf(float f) {
    union { float f; unsigned int u; } x; x.f = f;
    unsigned int u = x.u;
    u += 0x7fffu + ((u >> 16) & 1u);   // round-to-nearest-even
    return (unsigned short)(u >> 16);
}

// ---------------------------------------------------------------------------
// Prep: W1w[v][k][n] = sigmoid(adjw[v][k]) * W1[v][k-(k>v)][n]  (0 if k==v)
// stored in mfma_f32_16x16x32_bf16 B-fragment layout:
//   flat = (((v*32 + nt)*2 + ks)*64 + lane)*8 + e
//   where n = nt*16 + (lane&15), k = ks*32 + (lane>>4)*8 + e
// Block swizzle matches main_k: XCD x writes exactly the panels v in
// [x*8, x*8+8) that main_k's XCD x will read.
// ---------------------------------------------------------------------------
__global__ void prep_w1(const float* __restrict__ adjw,
                        const float* __restrict__ W1,
                        unsigned short* __restrict__ bfrag) {
    int nb   = (blockIdx.x & 7) * 128 + (blockIdx.x >> 3);   // bijective, 1024
    int tid  = nb * 256 + threadIdx.x;                       // 262144 threads
    int lane = tid & 63;
    int ks   = (tid >> 6) & 1;
    int nt   = (tid >> 7) & 31;
    int v    = tid >> 12;

    int n     = nt * 16 + (lane & 15);
    int kbase = ks * 32 + ((lane >> 4) << 3);

    u16x8 o;
#pragma unroll
    for (int e = 0; e < 8; ++e) {
        int k = kbase + e;
        float val = 0.f;
        if (k != v) {
            float aw = adjw[v * Vn + k];
            float s  = 1.f / (1.f + __expf(-aw));
            int  j   = k - (k > v);
            val = s * W1[((size_t)(v * (Vn - 1) + j)) * Hn + n];
        }
        o[e] = f2bf(val);
    }
    *reinterpret_cast<u16x8*>(bfrag + (size_t)tid * 8) = o;
}

// ---------------------------------------------------------------------------
// Main: block = 512 threads (8 waves) = one v, 8 row-groups of 64 rows.
// The 64KB B-panel for v is staged ONCE into LDS (reg-staged, coalesced) and
// shared by all 8 waves -> no redundant global B streams, loop reads LDS
// only. W2/b1 rows (2KB each) staged too. One barrier; loop is barrier-free.
// A fragments built in-register from x. 69.6KB LDS -> 2 blocks/CU
// = 4 waves/SIMD.
// ---------------------------------------------------------------------------
__global__ __launch_bounds__(512, 4)
void main_k(const float* __restrict__ x,
            const unsigned short* __restrict__ bfrag,
            const float* __restrict__ b1, const float* __restrict__ W2,
            const float* __restrict__ b2, float* __restrict__ out) {
    __shared__ __align__(16) unsigned char smem[69632];   // 64KB B + 2KB w2 + 2KB b1

    int t    = threadIdx.x;          // 0..511
    int wid  = t >> 6;               // 0..7
    int lane = t & 63;
    // bijective XCD swizzle: 512 blocks = 8 XCDs x 64; XCD x -> v in [x*8,x*8+8)
    int nb   = ((blockIdx.x & 7) << 6) + (blockIdx.x >> 3);
    int v    = nb >> 3;
    int rg   = ((nb & 7) << 3) + wid;   // 0..63: this wave's 64-row group

    // ---- issue panel staging loads (coalesced 16B/lane, 8KB/sweep) ----
    const u16x8* gpan = reinterpret_cast<const u16x8*>(bfrag) + (size_t)v * 4096;
    u16x8 stg[8];
#pragma unroll
    for (int i = 0; i < 8; ++i) stg[i] = gpan[i * 512 + t];

    // w2/b1 rows: waves 0-1 -> W2, waves 2-3 -> b1 (wave-uniform branches)
    int sel = t >> 7;
    f32x4 vstg;
    if (sel == 0)      vstg = reinterpret_cast<const f32x4*>(W2 + v * Hn)[t & 127];
    else if (sel == 1) vstg = reinterpret_cast<const f32x4*>(b1 + v * Hn)[t & 127];

    // ---- LDS writes (compiler inserts counted vmcnt waits) ----
    u16x8* lpan = reinterpret_cast<u16x8*>(smem);
#pragma unroll
    for (int i = 0; i < 8; ++i) lpan[i * 512 + t] = stg[i];
    if (sel == 0)      reinterpret_cast<f32x4*>(smem + 65536)[t & 127] = vstg;
    else if (sel == 1) reinterpret_cast<f32x4*>(smem + 67584)[t & 127] = vstg;

    // ---- A fragments from x: b = rg*64 + m*16 + (lane&15),
    //      k = ks*32 + (lane>>4)*8 + e  (overlaps barrier wait) ----
    bf16x8 a[4][2];
#pragma unroll
    for (int m = 0; m < 4; ++m)
#pragma unroll
        for (int ks = 0; ks < 2; ++ks) {
            int brow  = rg * 64 + m * 16 + (lane & 15);
            int kbase = ks * 32 + ((lane >> 4) << 3);
            const float* xp = x + (size_t)brow * Vn + kbase;
            f32x4 lo = *reinterpret_cast<const f32x4*>(xp);
            f32x4 hi = *reinterpret_cast<const f32x4*>(xp + 4);
            bfcast tc;
#pragma unroll
            for (int e = 0; e < 4; ++e) {
                tc.u[e]     = f2bf(lo[e]);
                tc.u[e + 4] = f2bf(hi[e]);
            }
            a[m][ks] = tc.b;
        }

    __syncthreads();

    // ---- main loop: 32 n-tiles, all operands from LDS, 2-deep prefetch ----
    const bf16x8* lb  = reinterpret_cast<const bf16x8*>(smem);
    const float*  w2l = reinterpret_cast<const float*>(smem + 65536);
    const float*  b1l = reinterpret_cast<const float*>(smem + 67584);
    int ncol = lane & 15;

    bf16x8 pb0[2], pb1[2];
    float  pw2[2], pbv[2];
    pb0[0] = lb[lane];
    pb1[0] = lb[64 + lane];
    pw2[0] = w2l[ncol];
    pbv[0] = b1l[ncol];

    float partial[4][4] = {};

#pragma unroll
    for (int j = 0; j < 32; ++j) {
        const int cur = j & 1, nxt = cur ^ 1;
        if (j < 31) {
            pb0[nxt] = lb[(j + 1) * 128 + lane];
            pb1[nxt] = lb[(j + 1) * 128 + 64 + lane];
            pw2[nxt] = w2l[(j + 1) * 16 + ncol];
            pbv[nxt] = b1l[(j + 1) * 16 + ncol];
        }
#pragma unroll
        for (int m = 0; m < 4; ++m) {
            f32x4 c = {pbv[cur], pbv[cur], pbv[cur], pbv[cur]};
            c = __builtin_amdgcn_mfma_f32_16x16x32_bf16(a[m][0], pb0[cur], c, 0, 0, 0);
            c = __builtin_amdgcn_mfma_f32_16x16x32_bf16(a[m][1], pb1[cur], c, 0, 0, 0);
#pragma unroll
            for (int r = 0; r < 4; ++r)
                partial[m][r] = fmaf(fmaxf(c[r], 0.f), pw2[cur], partial[m][r]);
        }
    }

    // reduce over the 16-lane column group (bits 0..3 of lane)
#pragma unroll
    for (int m = 0; m < 4; ++m)
#pragma unroll
        for (int r = 0; r < 4; ++r) {
            float s = partial[m][r];
            s += __shfl_xor(s, 1);
            s += __shfl_xor(s, 2);
            s += __shfl_xor(s, 4);
            s += __shfl_xor(s, 8);
            partial[m][r] = s;
        }

    float b2v = b2[v];
    if ((lane & 15) == 0) {
        int hi = lane >> 4;
#pragma unroll
        for (int m = 0; m < 4; ++m)
#pragma unroll
            for (int r = 0; r < 4; ++r) {
                int row = rg * 64 + m * 16 + hi * 4 + r;
                out[(size_t)row * Vn + v] = partial[m][r] + b2v;
            }
    }
}

extern "C" void kernel_launch(void* const* d_in, const int* in_sizes, int n_in,
                              void* d_out, int out_size, void* d_ws, size_t ws_size,
                              hipStream_t stream) {
    const float* x    = (const float*)d_in[0];
    const float* adjw = (const float*)d_in[1];
    const float* W1   = (const float*)d_in[2];
    const float* b1   = (const float*)d_in[3];
    const float* W2   = (const float*)d_in[4];
    const float* b2   = (const float*)d_in[5];
    float* out = (float*)d_out;

    // workspace: bfrag = 64*64*512 u16 (4 MiB)
    unsigned short* bfrag = (unsigned short*)d_ws;

    prep_w1<<<1024, 256, 0, stream>>>(adjw, W1, bfrag);
    main_k<<<512, 512, 0, stream>>>(x, bfrag, b1, W2, b2, out);
}

// Round 7
// 30.222 us; speedup vs baseline: 1.1658x; 1.1089x over previous
//
#include <hip/hip_runtime.h>
#include <hip/hip_bf16.h>

// Problem constants
constexpr int Bn = 4096;   // batch
constexpr int Vn = 64;     // nodes
constexpr int Hn = 512;    // hidden

typedef __attribute__((ext_vector_type(8))) short bf16x8;
typedef __attribute__((ext_vector_type(4))) float f32x4;
typedef __attribute__((ext_vector_type(8))) unsigned short u16x8;
typedef __attribute__((ext_vector_type(4))) _Float16 f16x4;

__device__ __forceinline__ unsigned short f2bf(float f) {
    union { float f; unsigned int u; } x; x.f = f;
    unsigned int u = x.u;
    u += 0x7fffu + ((u >> 16) & 1u);   // round-to-nearest-even
    return (unsigned short)(u >> 16);
}

// ---------------------------------------------------------------------------
// Fused prep (1152 blocks x 256):
//  blocks 0..1023: W1w[v][k][n] = sigmoid(adjw[v][k]) * W1[v][k-(k>v)][n]
//    in mfma B/A-frag layout: flat = (((v*32+nt)*2+ks)*64+lane)*8+e
//    n = nt*16+(lane&15), k = ks*32+(lane>>4)*8+e.  XCD-swizzled so panel v
//    is produced on XCD v>>3 (same XCD that consumes it in main_k).
//  blocks 1024..1151: x (fp32) -> afrag bf16, flat = ((mt*2+ks)*64+lane)*8+e,
//    b = mt*16+(lane&15), k = ks*32+(lane>>4)*8+e.
// ---------------------------------------------------------------------------
__global__ void prep_all(const float* __restrict__ adjw,
                         const float* __restrict__ W1,
                         const float* __restrict__ x,
                         unsigned short* __restrict__ bfrag,
                         unsigned short* __restrict__ afrag) {
    if (blockIdx.x < 1024) {
        int nb   = (blockIdx.x & 7) * 128 + (blockIdx.x >> 3);
        int tid  = nb * 256 + threadIdx.x;
        int lane = tid & 63;
        int ks   = (tid >> 6) & 1;
        int nt   = (tid >> 7) & 31;
        int v    = tid >> 12;

        int n     = nt * 16 + (lane & 15);
        int kbase = ks * 32 + ((lane >> 4) << 3);

        u16x8 o;
#pragma unroll
        for (int e = 0; e < 8; ++e) {
            int k = kbase + e;
            float val = 0.f;
            if (k != v) {
                float aw = adjw[v * Vn + k];
                float s  = 1.f / (1.f + __expf(-aw));
                int  j   = k - (k > v);
                val = s * W1[((size_t)(v * (Vn - 1) + j)) * Hn + n];
            }
            o[e] = f2bf(val);
        }
        *reinterpret_cast<u16x8*>(bfrag + (size_t)tid * 8) = o;
    } else {
        int tid  = (blockIdx.x - 1024) * 256 + threadIdx.x;   // 0..32767
        int lane = tid & 63;
        int ks   = (tid >> 6) & 1;
        int mt   = tid >> 7;

        int b     = mt * 16 + (lane & 15);
        int kbase = ks * 32 + ((lane >> 4) << 3);

        u16x8 o;
#pragma unroll
        for (int e = 0; e < 8; ++e)
            o[e] = f2bf(x[(size_t)b * Vn + kbase + e]);
        *reinterpret_cast<u16x8*>(afrag + (size_t)tid * 8) = o;
    }
}

// ---------------------------------------------------------------------------
// Main: block = (v, row-octant ro of 512 rows), 512 threads / 8 waves.
// Wave w owns n-cols [w*64, w*64+64): W1-frags (32 VGPR), w2 (f16), b1 —
// all persistent in registers. x streamed as bf16 A-frags via 16KB
// double-buffered LDS chunks (128 rows each). Per 16-row m-tile:
//   c' = mfma16x16x32(W1f, xf, b1bc)  x2   -> h with batch in lane&15
//   relu + cvt fp16 -> acc = mfma16x16x16f16(w2A, h, acc)  (dot with W2!)
// Cross-wave reduce via padded LDS partials [512][9], one final pass.
// No shuffle reduction, no c-init movs, epilogue = 8 VALU per c-tile.
// ---------------------------------------------------------------------------
__global__ __launch_bounds__(512, 4)
void main_k(const unsigned short* __restrict__ afrag,
            const unsigned short* __restrict__ bfrag,
            const float* __restrict__ b1, const float* __restrict__ W2,
            const float* __restrict__ b2, float* __restrict__ out) {
    __shared__ __align__(16) unsigned char smem[2 * 16384 + 512 * 9 * 4];

    int t    = threadIdx.x;
    int wid  = t >> 6;
    int lane = t & 63;
    // v lives on XCD v>>3 (matches prep's swizzle); ro = row octant
    int xcd  = blockIdx.x & 7;
    int idx  = blockIdx.x >> 3;
    int v    = xcd * 8 + (idx & 7);
    int ro   = idx >> 3;             // 0..7

    int hi4  = (lane >> 4) << 2;     // (lane>>4)*4

    // ---- persistent per-wave operands (issued first, long latency) ----
    const unsigned short* wpan = bfrag + (size_t)v * 32768;
    bf16x8 Wf[4][2];
#pragma unroll
    for (int j = 0; j < 4; ++j)
#pragma unroll
        for (int ks = 0; ks < 2; ++ks)
            Wf[j][ks] = *reinterpret_cast<const bf16x8*>(
                wpan + ((size_t)((wid * 4 + j) * 2 + ks)) * 512 + lane * 8);

    f32x4 b1bc[4];
    f16x4 w2A[4];
#pragma unroll
    for (int j = 0; j < 4; ++j) {
        int ntg = wid * 4 + j;
        b1bc[j] = *reinterpret_cast<const f32x4*>(b1 + v * Hn + ntg * 16 + hi4);
        f32x4 wv = *reinterpret_cast<const f32x4*>(W2 + v * Hn + ntg * 16 + hi4);
#pragma unroll
        for (int e = 0; e < 4; ++e) w2A[j][e] = (_Float16)wv[e];
    }

    // ---- stage chunk 0 (16KB linear copy from afrag) ----
    const unsigned char* asrc = reinterpret_cast<const unsigned char*>(afrag)
                              + (size_t)ro * 65536;
    {
        u16x8 s0 = *reinterpret_cast<const u16x8*>(asrc + t * 16);
        u16x8 s1 = *reinterpret_cast<const u16x8*>(asrc + 8192 + t * 16);
        *reinterpret_cast<u16x8*>(smem + t * 16) = s0;
        *reinterpret_cast<u16x8*>(smem + 8192 + t * 16) = s1;
    }
    __syncthreads();

    float* partials = reinterpret_cast<float*>(smem + 32768);

#pragma unroll
    for (int c = 0; c < 4; ++c) {
        // issue next chunk's loads before compute (latency hidden under MFMA)
        u16x8 s0, s1;
        if (c < 3) {
            s0 = *reinterpret_cast<const u16x8*>(asrc + (c + 1) * 16384 + t * 16);
            s1 = *reinterpret_cast<const u16x8*>(asrc + (c + 1) * 16384 + 8192 + t * 16);
        }

        const unsigned char* lb = smem + (c & 1) * 16384;
#pragma unroll
        for (int mt = 0; mt < 8; ++mt) {
            bf16x8 a0 = *reinterpret_cast<const bf16x8*>(lb + ((mt * 2 + 0) * 64 + lane) * 16);
            bf16x8 a1 = *reinterpret_cast<const bf16x8*>(lb + ((mt * 2 + 1) * 64 + lane) * 16);
            f32x4 acc = {0.f, 0.f, 0.f, 0.f};
#pragma unroll
            for (int j = 0; j < 4; ++j) {
                f32x4 c1 = __builtin_amdgcn_mfma_f32_16x16x32_bf16(Wf[j][0], a0, b1bc[j], 0, 0, 0);
                c1 = __builtin_amdgcn_mfma_f32_16x16x32_bf16(Wf[j][1], a1, c1, 0, 0, 0);
                f16x4 hb;
#pragma unroll
                for (int e = 0; e < 4; ++e)
                    hb[e] = (_Float16)fmaxf(c1[e], 0.f);
                acc = __builtin_amdgcn_mfma_f32_16x16x16f16(w2A[j], hb, acc, 0, 0, 0);
            }
            // D[i][b]: all i-rows equal; lanes 0..15 reg 0 hold row 0
            if (lane < 16)
                partials[(c * 128 + mt * 16 + lane) * 9 + wid] = acc[0];
        }

        if (c < 3) {
            unsigned char* nbuf = smem + ((c + 1) & 1) * 16384;
            *reinterpret_cast<u16x8*>(nbuf + t * 16) = s0;
            *reinterpret_cast<u16x8*>(nbuf + 8192 + t * 16) = s1;
        }
        __syncthreads();
    }

    // ---- final cross-wave reduce: thread t owns row ro*512+t ----
    float s = b2[v];
#pragma unroll
    for (int w = 0; w < 8; ++w) s += partials[t * 9 + w];
    out[(size_t)(ro * 512 + t) * Vn + v] = s;
}

extern "C" void kernel_launch(void* const* d_in, const int* in_sizes, int n_in,
                              void* d_out, int out_size, void* d_ws, size_t ws_size,
                              hipStream_t stream) {
    const float* x    = (const float*)d_in[0];
    const float* adjw = (const float*)d_in[1];
    const float* W1   = (const float*)d_in[2];
    const float* b1   = (const float*)d_in[3];
    const float* W2   = (const float*)d_in[4];
    const float* b2   = (const float*)d_in[5];
    float* out = (float*)d_out;

    // workspace: bfrag = 64*64*512 u16 (4 MiB), afrag = 4096*64 u16 (512 KiB)
    unsigned short* bfrag = (unsigned short*)d_ws;
    unsigned short* afrag = bfrag + (size_t)Vn * Vn * Hn;

    prep_all<<<1152, 256, 0, stream>>>(adjw, W1, x, bfrag, afrag);
    main_k<<<512, 512, 0, stream>>>(afrag, bfrag, b1, W2, b2, out);
}